// Round 8
// baseline (981.031 us; speedup 1.0000x reference)
//
#include <hip/hip_runtime.h>
#include <hip/hip_cooperative_groups.h>
#include <hip/hip_bf16.h>
#include <stdint.h>

// MPNN latency predictor, MI355X — round 8.
// vs R7: (1) ONE cooperative kernel (grid 256 x 512thr, 1 block/CU, grid.sync
// between phases) fuses counts + 3x(msg,node) + decoder -> 2 dispatches total.
// (2) msg: 2 M-frags per wave (32 edges/wave, 128 edges/block) -> each B-frag
// register load feeds 2 MFMAs, LDS read traffic halved (~1.1GB -> 545MB).

#define N_NODES 32768
#define N_EDGES 32768
#define STEPS 3

namespace cg = cooperative_groups;

typedef __attribute__((ext_vector_type(8))) short short8;   // 8 bf16 = 4 VGPRs
typedef __attribute__((ext_vector_type(4))) float float4v;  // MFMA C/D

__device__ __forceinline__ float bf2f(unsigned short u) {
    union { unsigned int i; float f; } v; v.i = ((unsigned int)u) << 16; return v.f;
}
__device__ __forceinline__ unsigned short f2bf(float f) {  // RNE
    union { float f; unsigned int i; } v; v.f = f;
    unsigned int x = v.i;
    return (unsigned short)((x + 0x7fffu + ((x >> 16) & 1u)) >> 16);
}
__device__ __forceinline__ unsigned int fbits(float f) {
    union { float f; unsigned int i; } v; v.f = f; return v.i;
}

// pack 8 products hv*hf[j] into a bf16x8 A-frag: round-half-up + v_perm pack
__device__ __forceinline__ short8 packA(float hv, const float* hf) {
    union { short8 v; unsigned int u[4]; } r;
#pragma unroll
    for (int p = 0; p < 4; p++) {
        unsigned int p0 = fbits(hv * hf[2 * p]) + 0x8000u;
        unsigned int p1 = fbits(hv * hf[2 * p + 1]) + 0x8000u;
        r.u[p] = __builtin_amdgcn_perm(p1, p0, 0x07060302u);  // {hi16(p0), hi16(p1)}
    }
    return r.v;
}

// async global->LDS, 16B/lane; lds dest = wave-uniform base + lane*16
__device__ __forceinline__ void gload_lds16(const void* g, void* l) {
    __builtin_amdgcn_global_load_lds(
        (__attribute__((address_space(1))) void*)g,
        (__attribute__((address_space(3))) void*)l, 16, 0, 0);
}

// ===================== fused setup kernel (unchanged from R7) ==============
__global__ __launch_bounds__(256) void k_setup(
    const float* __restrict__ root, const float* __restrict__ Wih,
    const float* __restrict__ Whh,
    const float* __restrict__ We2, const float* __restrict__ be2,
    const float* __restrict__ Wd1, const float* __restrict__ bd1,
    const float* __restrict__ Wd2,
    const float* __restrict__ x, const float* __restrict__ u,
    const float* __restrict__ Wp, const float* __restrict__ bp,
    const float* __restrict__ ea, const float* __restrict__ We1,
    const float* __restrict__ be1,
    unsigned short* __restrict__ rootTf, unsigned short* __restrict__ wcombf,
    unsigned short* __restrict__ w2tf,
    unsigned short* __restrict__ wd1f, unsigned short* __restrict__ wd2f,
    unsigned short* __restrict__ hb,
    unsigned short* __restrict__ hid, float* __restrict__ aggcnt)
{
    int b = blockIdx.x, tid = threadIdx.x;
    if (b < 144) {
        int i = b * 256 + tid;
        if (i < 4096) {
            int j = i & 7, lane = (i >> 3) & 63, g = i >> 9;   // g<8
            int kb = g >> 2, nf = g & 3;
            int o = nf * 16 + (lane & 15);
            int k = kb * 32 + (lane >> 4) * 8 + j;
            rootTf[i] = f2bf(root[k * 64 + o]);
        } else if (i < 4096 + 32768) {
            int t = i - 4096;
            int j = t & 7, lane = (t >> 3) & 63, g = t >> 9;   // g<64
            int kb = g >> 4, nf = g & 15;
            int cp = nf * 16 + (lane & 15);
            int k = kb * 32 + (lane >> 4) * 8 + j;
            float v;
            if (cp < 128)      v = (k < 64) ? Wih[cp * 64 + k] : Whh[cp * 64 + (k - 64)];
            else if (cp < 192) v = (k < 64) ? Wih[cp * 64 + k] : 0.f;
            else               v = (k < 64) ? 0.f : Whh[(cp - 64) * 64 + (k - 64)];
            wcombf[t] = f2bf(v);
        }
    } else if (b < 1184) {
        int t = (b - 144) * 256 + tid;   // t < 266240
        if (t < 65 * 4096) {
            int kk = t >> 12, r = t & 4095;
            int j = r & 7, lane = (r >> 3) & 63, g = r >> 9;  // g<8
            int half = g >> 2, nf = g & 3;
            int o = nf * 16 + (lane & 15);
            int hh = half * 32 + (lane >> 4) * 8 + j;
            float v = (kk < 64) ? We2[((size_t)(hh * 64 + o)) * 64 + kk]
                                : be2[(size_t)hh * 64 + o];
            w2tf[t] = f2bf(v);
        }
    } else if (b < 1232) {
        int i = (b - 1184) * 256 + tid;
        if (i < 10240) {
            int j = i & 7, lane = (i >> 3) & 63, g = i >> 9;  // g<20
            int kb = g >> 2, nf = g & 3;
            int o = nf * 16 + (lane & 15);
            int k = kb * 32 + (lane >> 4) * 8 + j;
            float v = (k < 133) ? Wd1[(size_t)o * 133 + k] : (k == 133 ? bd1[o] : 0.f);
            wd1f[i] = f2bf(v);
        } else if (i < 10240 + 2048) {
            int t = i - 10240;
            int j = t & 7, lane = (t >> 3) & 63, g = t >> 9;  // g<4
            int kb = g >> 1, nf = g & 1;
            int o = nf * 16 + (lane & 15);
            int k = kb * 32 + (lane >> 4) * 8 + j;
            wd2f[t] = f2bf(Wd2[(size_t)o * 64 + k]);
        }
    } else if (b < 9424) {
        int idx = (b - 1232) * 256 + tid;
        int n = idx >> 6, j = idx & 63;
        const float* wr = Wp + j * 23;
        const float* xr = x + (size_t)n * 12;
        float s = bp[j];
#pragma unroll
        for (int i = 0; i < 12; i++) s += xr[i] * wr[i];
#pragma unroll
        for (int i = 0; i < 11; i++) s += u[i] * wr[12 + i];
        hb[idx] = f2bf(tanhf(s));
    } else if (b < 17616) {
        int idx = (b - 9424) * 256 + tid;
        int e = idx >> 6, j = idx & 63;
        float s = be1[j];
#pragma unroll
        for (int i = 0; i < 5; i++) s += ea[(size_t)e * 5 + i] * We1[j * 5 + i];
        hid[idx] = f2bf(s > 0.f ? s : 0.f);
    } else {
        int idx = (b - 17616) * 1024 + tid * 4;
        if (idx < 2129920) {
            float4v z = {0.f, 0.f, 0.f, 0.f};
            *(float4v*)(aggcnt + idx) = z;
        }
    }
}

// ===================== cooperative main kernel =============================
// grid 256 x 512 threads (8 waves), 64KB static LDS, 1 block/CU co-resident.
// Phases: counts -> 3x(msg -> sync -> node -> sync) -> decoder.
__global__ __launch_bounds__(512, 2) void k_main(
    const unsigned short* __restrict__ hid,
    unsigned short* __restrict__ hb,
    const unsigned short* __restrict__ w2tf,
    const int* __restrict__ ei,
    float* __restrict__ agg, float* __restrict__ cnts,
    const unsigned short* __restrict__ rootTf,
    const unsigned short* __restrict__ wcombf,
    const float* __restrict__ conv_b,
    const float* __restrict__ bih, const float* __restrict__ bhh,
    const float* __restrict__ ea,
    const unsigned short* __restrict__ wd1f,
    const unsigned short* __restrict__ wd2f,
    const float* __restrict__ bd2,
    const float* __restrict__ Wd3, const float* __restrict__ bd3,
    float* __restrict__ out)
{
    cg::grid_group grid = cg::this_grid();
    __shared__ unsigned short smem[2][2][8192];   // 64KB, reused per phase
    int tid = threadIdx.x, wave = tid >> 6, lane = tid & 63;
    int l15 = lane & 15, quad = lane >> 4;

    // ---- phase 0: counts ----
    {
        int gtid = blockIdx.x * 512 + tid;
        if (gtid < N_EDGES) atomicAdd(&cnts[ei[N_EDGES + gtid]], 1.0f);
    }
    // no sync needed yet: counts first read in node phase (after msg's sync)

    for (int step = 0; step < STEPS; step++) {
        // ============ msg phase: 128 edges/block, 2 M-frags per wave =======
        {
            int mf = wave & 3, kh = wave >> 2;
            int ebase = blockIdx.x * 128 + mf * 32;
            int src0 = ei[ebase + l15], src1 = ei[ebase + 16 + l15];

            union Hrow { short8 v[4]; unsigned short u[32]; };
            Hrow hrow[2];
#pragma unroll
            for (int i = 0; i < 4; i++) {
                hrow[0].v[i] = *(const short8*)(hid + (size_t)(ebase + l15) * 64 + kh * 32 + i * 8);
                hrow[1].v[i] = *(const short8*)(hid + (size_t)(ebase + 16 + l15) * 64 + kh * 32 + i * 8);
            }
            float hf[2][2][8];
#pragma unroll
            for (int f = 0; f < 2; f++) {
                int src = f ? src1 : src0;
                short8 h0 = *(const short8*)(hb + (size_t)src * 64 + quad * 8);
                short8 h1 = *(const short8*)(hb + (size_t)src * 64 + 32 + quad * 8);
#pragma unroll
                for (int j = 0; j < 8; j++) {
                    hf[f][0][j] = bf2f((unsigned short)h0[j]);
                    hf[f][1][j] = bf2f((unsigned short)h1[j]);
                }
            }

            int kk0 = kh ? 32 : 0;
            auto stage = [&](int pair, int db) {
                const unsigned short* g = w2tf + (size_t)(kk0 + 2 * pair) * 4096;
#pragma unroll
                for (int c = 0; c < 4; c++) {
                    int chunk = mf * 4 + c;
                    gload_lds16(g + (size_t)chunk * 512 + lane * 8, &smem[kh][db][chunk * 512]);
                }
            };
            stage(0, 0);

            float4v acc[2][4] = {};
            int cur = 0;
#pragma unroll
            for (int i = 0; i <= 16; i++) {
                __syncthreads();
                if ((kh == 0 && i + 1 < 16) || (kh == 1 && i + 1 <= 16))
                    stage(i + 1, cur ^ 1);
                int nkk = (kh == 0) ? (i < 16 ? 2 : 0) : (i < 16 ? 2 : 1);
                for (int s = 0; s < nkk; s++) {
                    const unsigned short* bp = &smem[kh][cur][s * 4096];
                    short8 b0[4], b1[4];
#pragma unroll
                    for (int nf = 0; nf < 4; nf++) {
                        b0[nf] = *(const short8*)(bp + (0 * 4 + nf) * 512 + lane * 8);
                        b1[nf] = *(const short8*)(bp + (1 * 4 + nf) * 512 + lane * 8);
                    }
#pragma unroll
                    for (int f = 0; f < 2; f++) {
                        float hv = (kh == 1 && i == 16) ? 1.0f : bf2f(hrow[f].u[2 * i + s]);
                        short8 a0 = packA(hv, hf[f][0]);
                        short8 a1 = packA(hv, hf[f][1]);
#pragma unroll
                        for (int nf = 0; nf < 4; nf++)
                            acc[f][nf] = __builtin_amdgcn_mfma_f32_16x16x32_bf16(a0, b0[nf], acc[f][nf], 0, 0, 0);
#pragma unroll
                        for (int nf = 0; nf < 4; nf++)
                            acc[f][nf] = __builtin_amdgcn_mfma_f32_16x16x32_bf16(a1, b1[nf], acc[f][nf], 0, 0, 0);
                    }
                }
                cur ^= 1;
            }

            // merge kh partials via LDS (32KB region), kh0 issues atomics
            __syncthreads();
            float* mg = (float*)&smem[0][0][0];
            if (kh == 1) {
#pragma unroll
                for (int f = 0; f < 2; f++)
#pragma unroll
                    for (int nf = 0; nf < 4; nf++)
#pragma unroll
                        for (int r = 0; r < 4; r++)
                            mg[(mf * 2 + f) * 1024 + lane * 16 + nf * 4 + r] = acc[f][nf][r];
            }
            __syncthreads();
            if (kh == 0) {
#pragma unroll
                for (int f = 0; f < 2; f++) {
                    int dsts[4];
#pragma unroll
                    for (int r = 0; r < 4; r++)
                        dsts[r] = ei[N_EDGES + ebase + f * 16 + quad * 4 + r];
#pragma unroll
                    for (int nf = 0; nf < 4; nf++)
#pragma unroll
                        for (int r = 0; r < 4; r++)
                            atomicAdd(agg + (size_t)dsts[r] * 64 + nf * 16 + l15,
                                      acc[f][nf][r] + mg[(mf * 2 + f) * 1024 + lane * 16 + nf * 4 + r]);
                }
            }
        }
        __threadfence();
        grid.sync();

        // ============ node phase: 128 nodes/block, 16 nodes/wave ===========
        {
            unsigned short* m_lds = (unsigned short*)&smem[0][0][0];  // 128*72
            int node0 = blockIdx.x * 128;
            int row0 = wave * 16;

            float4v acc1[4] = {};
            {
                short8 a1[2];
#pragma unroll
                for (int kb = 0; kb < 2; kb++)
                    a1[kb] = *(const short8*)(hb + (size_t)(node0 + row0 + l15) * 64 + kb * 32 + quad * 8);
#pragma unroll
                for (int kb = 0; kb < 2; kb++)
#pragma unroll
                    for (int nf = 0; nf < 4; nf++) {
                        short8 b = *(const short8*)(rootTf + (size_t)((kb * 4 + nf) * 64 + lane) * 8);
                        acc1[nf] = __builtin_amdgcn_mfma_f32_16x16x32_bf16(a1[kb], b, acc1[nf], 0, 0, 0);
                    }
            }
#pragma unroll
            for (int rr = 0; rr < 4; rr++) {
                int nl = row0 + quad * 4 + rr;
                float cnt = cnts[node0 + nl]; if (cnt < 1.f) cnt = 1.f;
                float rcp = 1.f / cnt;
#pragma unroll
                for (int nf = 0; nf < 4; nf++) {
                    int c = nf * 16 + l15;
                    float* ap = agg + (size_t)(node0 + nl) * 64 + c;
                    float av = *ap;
                    *ap = 0.f;
                    float mv = av * rcp + acc1[nf][rr] + conv_b[c];
                    m_lds[nl * 72 + c] = f2bf(mv > 0.f ? mv : 0.f);
                }
            }
            __syncthreads();

            float4v acc2[16] = {};
#pragma unroll
            for (int kb = 0; kb < 4; kb++) {
                short8 a2;
                if (kb < 2)
                    a2 = *(const short8*)(m_lds + (row0 + l15) * 72 + kb * 32 + quad * 8);
                else
                    a2 = *(const short8*)(hb + (size_t)(node0 + row0 + l15) * 64 + (kb - 2) * 32 + quad * 8);
#pragma unroll
                for (int nf = 0; nf < 16; nf++) {
                    short8 b = *(const short8*)(wcombf + (size_t)((kb * 16 + nf) * 64 + lane) * 8);
                    acc2[nf] = __builtin_amdgcn_mfma_f32_16x16x32_bf16(a2, b, acc2[nf], 0, 0, 0);
                }
            }
#pragma unroll
            for (int nf0 = 0; nf0 < 4; nf0++) {
                int c = nf0 * 16 + l15;
                float br = bih[c] + bhh[c];
                float bz = bih[64 + c] + bhh[64 + c];
                float bni = bih[128 + c], bnh = bhh[128 + c];
#pragma unroll
                for (int rr = 0; rr < 4; rr++) {
                    int node = node0 + row0 + quad * 4 + rr;
                    float gr = 1.f / (1.f + __expf(-(acc2[nf0][rr] + br)));
                    float gz = 1.f / (1.f + __expf(-(acc2[nf0 + 4][rr] + bz)));
                    float ng = tanhf(acc2[nf0 + 8][rr] + bni + gr * (acc2[nf0 + 12][rr] + bnh));
                    float ho = bf2f(hb[(size_t)node * 64 + c]);
                    float hn = (1.f - gz) * ng + gz * ho;
                    hb[(size_t)node * 64 + c] = f2bf(hn);
                }
            }
        }
        __threadfence();
        grid.sync();
    }

    // ============ decoder phase: 128 edges/block, 16 edges/wave ============
    {
        unsigned short* d1f = (unsigned short*)&smem[0][0][0];      // [8][1024]
        float* d2s = (float*)((char*)&smem[0][0][0] + 16384);       // [8][528]
        int ebase = blockIdx.x * 128 + wave * 16;
        int e = ebase + l15;
        int src = ei[e], dst = ei[N_EDGES + e];

        short8 a[5];
#pragma unroll
        for (int kb = 0; kb < 2; kb++) {
            a[kb]     = *(const short8*)(hb + (size_t)src * 64 + kb * 32 + quad * 8);
            a[2 + kb] = *(const short8*)(hb + (size_t)dst * 64 + kb * 32 + quad * 8);
        }
        {
            union { short8 v; unsigned short u[8]; } tea;
#pragma unroll
            for (int j = 0; j < 8; j++) {
                float vv = 0.f;
                if (quad == 0) vv = (j < 5) ? ea[(size_t)e * 5 + j] : (j == 5 ? 1.f : 0.f);
                tea.u[j] = f2bf(vv);
            }
            a[4] = tea.v;
        }

        float4v acc1[4] = {};
#pragma unroll
        for (int kb = 0; kb < 5; kb++)
#pragma unroll
            for (int nf = 0; nf < 4; nf++) {
                short8 b = *(const short8*)(wd1f + (size_t)((kb * 4 + nf) * 64 + lane) * 8);
                acc1[nf] = __builtin_amdgcn_mfma_f32_16x16x32_bf16(a[kb], b, acc1[nf], 0, 0, 0);
            }
#pragma unroll
        for (int nf = 0; nf < 4; nf++) {
            int kbp = nf >> 1;
            int lanep_hi = ((nf & 1) * 2 + (l15 >> 3)) * 16;
            int jp = l15 & 7;
#pragma unroll
            for (int r = 0; r < 4; r++) {
                float v = acc1[nf][r];
                d1f[wave * 1024 + kbp * 512 + (lanep_hi + quad * 4 + r) * 8 + jp] = f2bf(v > 0.f ? v : 0.f);
            }
        }
        float4v acc2[2] = {};
#pragma unroll
        for (int kb = 0; kb < 2; kb++) {
            short8 a2 = *(const short8*)(&d1f[wave * 1024 + kb * 512 + lane * 8]);
#pragma unroll
            for (int nf = 0; nf < 2; nf++) {
                short8 b = *(const short8*)(wd2f + (size_t)((kb * 2 + nf) * 64 + lane) * 8);
                acc2[nf] = __builtin_amdgcn_mfma_f32_16x16x32_bf16(a2, b, acc2[nf], 0, 0, 0);
            }
        }
#pragma unroll
        for (int nf = 0; nf < 2; nf++) {
            int c = nf * 16 + l15;
            float bias = bd2[c];
#pragma unroll
            for (int r = 0; r < 4; r++) {
                float v = acc2[nf][r] + bias;
                d2s[wave * 528 + (quad * 4 + r) * 33 + c] = v > 0.f ? v : 0.f;
            }
        }
        {
            int e_l = lane >> 2, t = lane & 3;
            float s = bd3[t];
            const float* w3 = Wd3 + t * 32;
            const float* dr = &d2s[wave * 528 + e_l * 33];
#pragma unroll
            for (int k = 0; k < 32; k++) s += w3[k] * dr[k];
            out[(size_t)(ebase + e_l) * 4 + t] = s;
        }
    }
}

extern "C" void kernel_launch(void* const* d_in, const int* in_sizes, int n_in,
                              void* d_out, int out_size, void* d_ws, size_t ws_size,
                              hipStream_t stream)
{
    const float* x      = (const float*)d_in[0];
    const int*   ei     = (const int*)d_in[1];
    const float* ea     = (const float*)d_in[2];
    const float* u      = (const float*)d_in[3];
    const float* Wp     = (const float*)d_in[4];
    const float* bp     = (const float*)d_in[5];
    const float* We1    = (const float*)d_in[6];
    const float* be1    = (const float*)d_in[7];
    const float* We2    = (const float*)d_in[8];
    const float* be2    = (const float*)d_in[9];
    const float* root   = (const float*)d_in[10];
    const float* conv_b = (const float*)d_in[11];
    const float* Wih    = (const float*)d_in[12];
    const float* bih    = (const float*)d_in[13];
    const float* Whh    = (const float*)d_in[14];
    const float* bhh    = (const float*)d_in[15];
    const float* Wd1    = (const float*)d_in[16];
    const float* bd1    = (const float*)d_in[17];
    const float* Wd2    = (const float*)d_in[18];
    const float* bd2    = (const float*)d_in[19];
    const float* Wd3    = (const float*)d_in[20];
    const float* bd3    = (const float*)d_in[21];
    float* out = (float*)d_out;

    char* ws = (char*)d_ws;
    size_t off = 0;
    auto take = [&](size_t bytes) -> char* {
        char* p = ws + off; off = (off + bytes + 255) & ~(size_t)255; return p;
    };
    unsigned short* hb     = (unsigned short*)take((size_t)N_NODES * 64 * 2);
    unsigned short* hid    = (unsigned short*)take((size_t)N_EDGES * 64 * 2);
    float*          aggcnt = (float*)take((size_t)(N_NODES * 64 + N_NODES) * 4);
    float*          agg    = aggcnt;
    float*          cnts   = aggcnt + (size_t)N_NODES * 64;
    unsigned short* w2tf   = (unsigned short*)take((size_t)66 * 4096 * 2);  // +1 pad blk
    unsigned short* rootTf = (unsigned short*)take((size_t)4096 * 2);
    unsigned short* wcombf = (unsigned short*)take((size_t)32768 * 2);
    unsigned short* wd1f   = (unsigned short*)take((size_t)10240 * 2);
    unsigned short* wd2f   = (unsigned short*)take((size_t)2048 * 2);
    (void)ws_size;

    k_setup<<<19696, 256, 0, stream>>>(root, Wih, Whh, We2, be2, Wd1, bd1, Wd2,
                                       x, u, Wp, bp, ea, We1, be1,
                                       rootTf, wcombf, w2tf, wd1f, wd2f,
                                       hb, hid, aggcnt);

    void* args[] = {
        (void*)&hid, (void*)&hb, (void*)&w2tf, (void*)&ei,
        (void*)&agg, (void*)&cnts, (void*)&rootTf, (void*)&wcombf,
        (void*)&conv_b, (void*)&bih, (void*)&bhh, (void*)&ea,
        (void*)&wd1f, (void*)&wd2f, (void*)&bd2,
        (void*)&Wd3, (void*)&bd3, (void*)&out
    };
    hipLaunchCooperativeKernel((const void*)k_main, dim3(256), dim3(512),
                               args, 0, stream);
}

// Round 11
// 332.784 us; speedup vs baseline: 2.9480x; 2.9480x over previous
//
#include <hip/hip_runtime.h>
#include <hip/hip_bf16.h>
#include <stdint.h>

// MPNN latency predictor, MI355X — round 11.
// = R9/R10 design (2 M-frags/wave msg, split kernels) with ONE hedge: the msg
// i-loop is NOT #pragma unroll'ed (R9/R10 both died with "container failed
// twice"; suspected hipcc code-size/compile-time pathology from the 17x
// unrolled 2-frag body). Loop conditions are wave-uniform; rolled loop costs
// only scalar ops. Design rationale vs R8 failure (cooperative mega-fusion ->
// w2tf stream fell out of L2, 367MB HBM FETCH): split kernels restore the
// L2-served broadcast; 2 M-frags/wave halves LDS reads (1.06M -> 0.53M).

#define N_NODES 32768
#define N_EDGES 32768
#define STEPS 3

typedef __attribute__((ext_vector_type(8))) short short8;   // 8 bf16 = 4 VGPRs
typedef __attribute__((ext_vector_type(4))) float float4v;  // MFMA C/D

__device__ __forceinline__ float bf2f(unsigned short u) {
    union { unsigned int i; float f; } v; v.i = ((unsigned int)u) << 16; return v.f;
}
__device__ __forceinline__ unsigned short f2bf(float f) {  // RNE
    union { float f; unsigned int i; } v; v.f = f;
    unsigned int x = v.i;
    return (unsigned short)((x + 0x7fffu + ((x >> 16) & 1u)) >> 16);
}
__device__ __forceinline__ unsigned int fbits(float f) {
    union { float f; unsigned int i; } v; v.f = f; return v.i;
}

// pack 8 products hv*hf[j] into a bf16x8 A-frag: round-half-up + v_perm pack
__device__ __forceinline__ short8 packA(float hv, const float* hf) {
    union { short8 v; unsigned int u[4]; } r;
#pragma unroll
    for (int p = 0; p < 4; p++) {
        unsigned int p0 = fbits(hv * hf[2 * p]) + 0x8000u;
        unsigned int p1 = fbits(hv * hf[2 * p + 1]) + 0x8000u;
        r.u[p] = __builtin_amdgcn_perm(p1, p0, 0x07060302u);  // {hi16(p0), hi16(p1)}
    }
    return r.v;
}

// async global->LDS, 16B/lane; lds dest = wave-uniform base + lane*16
__device__ __forceinline__ void gload_lds16(const void* g, void* l) {
    __builtin_amdgcn_global_load_lds(
        (__attribute__((address_space(1))) void*)g,
        (__attribute__((address_space(3))) void*)l, 16, 0, 0);
}

// ===================== fused setup kernel (R7) =============================
__global__ __launch_bounds__(256) void k_setup(
    const float* __restrict__ root, const float* __restrict__ Wih,
    const float* __restrict__ Whh,
    const float* __restrict__ We2, const float* __restrict__ be2,
    const float* __restrict__ Wd1, const float* __restrict__ bd1,
    const float* __restrict__ Wd2,
    const float* __restrict__ x, const float* __restrict__ u,
    const float* __restrict__ Wp, const float* __restrict__ bp,
    const float* __restrict__ ea, const float* __restrict__ We1,
    const float* __restrict__ be1,
    unsigned short* __restrict__ rootTf, unsigned short* __restrict__ wcombf,
    unsigned short* __restrict__ w2tf,
    unsigned short* __restrict__ wd1f, unsigned short* __restrict__ wd2f,
    unsigned short* __restrict__ hb,
    unsigned short* __restrict__ hid, float* __restrict__ aggcnt)
{
    int b = blockIdx.x, tid = threadIdx.x;
    if (b < 144) {
        int i = b * 256 + tid;
        if (i < 4096) {
            int j = i & 7, lane = (i >> 3) & 63, g = i >> 9;   // g<8
            int kb = g >> 2, nf = g & 3;
            int o = nf * 16 + (lane & 15);
            int k = kb * 32 + (lane >> 4) * 8 + j;
            rootTf[i] = f2bf(root[k * 64 + o]);
        } else if (i < 4096 + 32768) {
            int t = i - 4096;
            int j = t & 7, lane = (t >> 3) & 63, g = t >> 9;   // g<64
            int kb = g >> 4, nf = g & 15;
            int cp = nf * 16 + (lane & 15);
            int k = kb * 32 + (lane >> 4) * 8 + j;
            float v;
            if (cp < 128)      v = (k < 64) ? Wih[cp * 64 + k] : Whh[cp * 64 + (k - 64)];
            else if (cp < 192) v = (k < 64) ? Wih[cp * 64 + k] : 0.f;
            else               v = (k < 64) ? 0.f : Whh[(cp - 64) * 64 + (k - 64)];
            wcombf[t] = f2bf(v);
        }
    } else if (b < 1184) {
        int t = (b - 144) * 256 + tid;   // t < 266240
        if (t < 65 * 4096) {
            int kk = t >> 12, r = t & 4095;
            int j = r & 7, lane = (r >> 3) & 63, g = r >> 9;  // g<8
            int half = g >> 2, nf = g & 3;
            int o = nf * 16 + (lane & 15);
            int hh = half * 32 + (lane >> 4) * 8 + j;
            float v = (kk < 64) ? We2[((size_t)(hh * 64 + o)) * 64 + kk]
                                : be2[(size_t)hh * 64 + o];
            w2tf[t] = f2bf(v);
        }
    } else if (b < 1232) {
        int i = (b - 1184) * 256 + tid;
        if (i < 10240) {
            int j = i & 7, lane = (i >> 3) & 63, g = i >> 9;  // g<20
            int kb = g >> 2, nf = g & 3;
            int o = nf * 16 + (lane & 15);
            int k = kb * 32 + (lane >> 4) * 8 + j;
            float v = (k < 133) ? Wd1[(size_t)o * 133 + k] : (k == 133 ? bd1[o] : 0.f);
            wd1f[i] = f2bf(v);
        } else if (i < 10240 + 2048) {
            int t = i - 10240;
            int j = t & 7, lane = (t >> 3) & 63, g = t >> 9;  // g<4
            int kb = g >> 1, nf = g & 1;
            int o = nf * 16 + (lane & 15);
            int k = kb * 32 + (lane >> 4) * 8 + j;
            wd2f[t] = f2bf(Wd2[(size_t)o * 64 + k]);
        }
    } else if (b < 9424) {
        int idx = (b - 1232) * 256 + tid;
        int n = idx >> 6, j = idx & 63;
        const float* wr = Wp + j * 23;
        const float* xr = x + (size_t)n * 12;
        float s = bp[j];
#pragma unroll
        for (int i = 0; i < 12; i++) s += xr[i] * wr[i];
#pragma unroll
        for (int i = 0; i < 11; i++) s += u[i] * wr[12 + i];
        hb[idx] = f2bf(tanhf(s));
    } else if (b < 17616) {
        int idx = (b - 9424) * 256 + tid;
        int e = idx >> 6, j = idx & 63;
        float s = be1[j];
#pragma unroll
        for (int i = 0; i < 5; i++) s += ea[(size_t)e * 5 + i] * We1[j * 5 + i];
        hid[idx] = f2bf(s > 0.f ? s : 0.f);
    } else {
        int idx = (b - 17616) * 1024 + tid * 4;
        if (idx < 2129920) {
            float4v z = {0.f, 0.f, 0.f, 0.f};
            *(float4v*)(aggcnt + idx) = z;
        }
    }
}

__global__ __launch_bounds__(256) void k_counts(
    const int* __restrict__ ei, float* __restrict__ counts)
{
    int i = blockIdx.x * 256 + threadIdx.x;
    if (i < N_EDGES) atomicAdd(&counts[ei[N_EDGES + i]], 1.0f);
}

// ===================== fused msg GEMM ======================================
// 256 threads = 4 waves: wave = kh*2 + mf. 64 edges/block; each wave owns TWO
// 16-edge M-frags (f=0,1) so each B-frag LDS read feeds 2 MFMAs. kh picks the
// K-half (kh0: kk 0..31, kh1: kk 32..64 incl bias). Two kk per barrier: each
// kh stages a contiguous 16KB kk-pair (double-buffered, 64KB LDS, 2 blk/CU).
// i-loop deliberately NOT unrolled (compile-size hedge; conditions are
// wave-uniform scalars). kh partials merged in LDS (stride-17, conflict-free).
__global__ __launch_bounds__(256) void k_msg_fused(
    const unsigned short* __restrict__ hid,   // (E,64) bf16
    const unsigned short* __restrict__ hb,    // (N,64) bf16
    const unsigned short* __restrict__ w2tf,  // (66*4096) frag-interleaved
    const int* __restrict__ ei,
    float* __restrict__ agg)
{
    __shared__ unsigned short buf[2][2][8192];   // [kh][dbuf][16KB] = 64KB
    int tid = threadIdx.x, wave = tid >> 6, lane = tid & 63;
    int l15 = lane & 15, quad = lane >> 4;
    int mf = wave & 1, kh = wave >> 1;
    int ebase = blockIdx.x * 64 + mf * 32;

    union Hrow { short8 v[4]; unsigned short u[32]; };
    Hrow hrow[2];
    float hf[2][2][8];
#pragma unroll
    for (int f = 0; f < 2; f++) {
        int e_a = ebase + f * 16 + l15;
#pragma unroll
        for (int i = 0; i < 4; i++)
            hrow[f].v[i] = *(const short8*)(hid + (size_t)e_a * 64 + kh * 32 + i * 8);
        int src = ei[e_a];
        short8 h0 = *(const short8*)(hb + (size_t)src * 64 + quad * 8);
        short8 h1 = *(const short8*)(hb + (size_t)src * 64 + 32 + quad * 8);
#pragma unroll
        for (int j = 0; j < 8; j++) {
            hf[f][0][j] = bf2f((unsigned short)h0[j]);
            hf[f][1][j] = bf2f((unsigned short)h1[j]);
        }
    }

    int kk0 = kh ? 32 : 0;
    // stage kk-pair `pair` (16KB = 16 chunks of 1KB); wave mf stages 8 chunks
    auto stage = [&](int pair, int db) {
        const unsigned short* g = w2tf + (size_t)(kk0 + 2 * pair) * 4096;
#pragma unroll
        for (int c = 0; c < 8; c++) {
            int chunk = mf * 8 + c;
            gload_lds16(g + (size_t)chunk * 512 + lane * 8, &buf[kh][db][chunk * 512]);
        }
    };
    stage(0, 0);

    float4v acc[2][4] = {};
    int cur = 0;
    for (int i = 0; i <= 16; i++) {          // NOT unrolled (compile hedge)
        __syncthreads();   // staging of buf[*][cur] complete; prev reads done
        if ((kh == 0 && i + 1 < 16) || (kh == 1 && i + 1 <= 16))
            stage(i + 1, cur ^ 1);
        int nkk = (kh == 0) ? (i < 16 ? 2 : 0) : (i < 16 ? 2 : 1);  // wave-uniform
        for (int s = 0; s < nkk; s++) {
            const unsigned short* bp = &buf[kh][cur][s * 4096];
            short8 b0[4], b1[4];
#pragma unroll
            for (int nf = 0; nf < 4; nf++) {
                b0[nf] = *(const short8*)(bp + (0 * 4 + nf) * 512 + lane * 8);
                b1[nf] = *(const short8*)(bp + (1 * 4 + nf) * 512 + lane * 8);
            }
#pragma unroll
            for (int f = 0; f < 2; f++) {
                float hv = (kh == 1 && i == 16) ? 1.0f : bf2f(hrow[f].u[(2 * i + s) & 31]);
                short8 a0 = packA(hv, hf[f][0]);
                short8 a1 = packA(hv, hf[f][1]);
#pragma unroll
                for (int nf = 0; nf < 4; nf++)
                    acc[f][nf] = __builtin_amdgcn_mfma_f32_16x16x32_bf16(a0, b0[nf], acc[f][nf], 0, 0, 0);
#pragma unroll
                for (int nf = 0; nf < 4; nf++)
                    acc[f][nf] = __builtin_amdgcn_mfma_f32_16x16x32_bf16(a1, b1[nf], acc[f][nf], 0, 0, 0);
            }
        }
        cur ^= 1;
    }

    // merge kh partials via LDS: row = (mf*2+f)*64+lane, stride 17 (odd ->
    // conflict-free), 16 payload + 1 pad. 256 rows x 17 x 4B = 17.4KB.
    __syncthreads();
    float* mg = (float*)&buf[0][0][0];
    if (kh == 1) {
#pragma unroll
        for (int f = 0; f < 2; f++)
#pragma unroll
            for (int nf = 0; nf < 4; nf++)
#pragma unroll
                for (int r = 0; r < 4; r++)
                    mg[((mf * 2 + f) * 64 + lane) * 17 + nf * 4 + r] = acc[f][nf][r];
    }
    __syncthreads();
    if (kh == 0) {
#pragma unroll
        for (int f = 0; f < 2; f++) {
            int dsts[4];
#pragma unroll
            for (int r = 0; r < 4; r++)
                dsts[r] = ei[N_EDGES + ebase + f * 16 + quad * 4 + r];
#pragma unroll
            for (int nf = 0; nf < 4; nf++)
#pragma unroll
                for (int r = 0; r < 4; r++)
                    atomicAdd(agg + (size_t)dsts[r] * 64 + nf * 16 + l15,
                              acc[f][nf][r] + mg[((mf * 2 + f) * 64 + lane) * 17 + nf * 4 + r]);
        }
    }
}

// ===================== fused node update (R7) ==============================
__global__ __launch_bounds__(256) void k_node(
    const unsigned short* __restrict__ hb_in,
    const unsigned short* __restrict__ rootTf,
    const unsigned short* __restrict__ wcombf,
    float* __restrict__ agg, const float* __restrict__ counts,
    const float* __restrict__ conv_b,
    const float* __restrict__ bih, const float* __restrict__ bhh,
    unsigned short* __restrict__ hb_out)
{
    __shared__ unsigned short m_lds[64 * 72];
    int tid = threadIdx.x, w = tid >> 6, lane = tid & 63;
    int l15 = lane & 15, quad = lane >> 4;
    int node0 = blockIdx.x * 64;
    int row0 = w * 16;

    float4v acc1[4] = {};
    {
        short8 a1[2];
#pragma unroll
        for (int kb = 0; kb < 2; kb++)
            a1[kb] = *(const short8*)(hb_in + (size_t)(node0 + row0 + l15) * 64 + kb * 32 + quad * 8);
#pragma unroll
        for (int kb = 0; kb < 2; kb++)
#pragma unroll
            for (int nf = 0; nf < 4; nf++) {
                short8 b = *(const short8*)(rootTf + (size_t)((kb * 4 + nf) * 64 + lane) * 8);
                acc1[nf] = __builtin_amdgcn_mfma_f32_16x16x32_bf16(a1[kb], b, acc1[nf], 0, 0, 0);
            }
    }
#pragma unroll
    for (int rr = 0; rr < 4; rr++) {
        int nl = row0 + quad * 4 + rr;
        float cnt = counts[node0 + nl]; if (cnt < 1.f) cnt = 1.f;
        float rcp = 1.f / cnt;
#pragma unroll
        for (int nf = 0; nf < 4; nf++) {
            int c = nf * 16 + l15;
            float* ap = agg + (size_t)(node0 + nl) * 64 + c;
            float av = *ap;
            *ap = 0.f;
            float mv = av * rcp + acc1[nf][rr] + conv_b[c];
            m_lds[nl * 72 + c] = f2bf(mv > 0.f ? mv : 0.f);
        }
    }
    __syncthreads();

    float4v acc2[16] = {};
#pragma unroll
    for (int kb = 0; kb < 4; kb++) {
        short8 a2;
        if (kb < 2)
            a2 = *(const short8*)(m_lds + (row0 + l15) * 72 + kb * 32 + quad * 8);
        else
            a2 = *(const short8*)(hb_in + (size_t)(node0 + row0 + l15) * 64 + (kb - 2) * 32 + quad * 8);
#pragma unroll
        for (int nf = 0; nf < 16; nf++) {
            short8 b = *(const short8*)(wcombf + (size_t)((kb * 16 + nf) * 64 + lane) * 8);
            acc2[nf] = __builtin_amdgcn_mfma_f32_16x16x32_bf16(a2, b, acc2[nf], 0, 0, 0);
        }
    }

#pragma unroll
    for (int nf0 = 0; nf0 < 4; nf0++) {
        int c = nf0 * 16 + l15;
        float br = bih[c] + bhh[c];
        float bz = bih[64 + c] + bhh[64 + c];
        float bni = bih[128 + c], bnh = bhh[128 + c];
#pragma unroll
        for (int rr = 0; rr < 4; rr++) {
            int node = node0 + row0 + quad * 4 + rr;
            float gr = 1.f / (1.f + __expf(-(acc2[nf0][rr] + br)));
            float gz = 1.f / (1.f + __expf(-(acc2[nf0 + 4][rr] + bz)));
            float ng = tanhf(acc2[nf0 + 8][rr] + bni + gr * (acc2[nf0 + 12][rr] + bnh));
            float ho = bf2f(hb_in[(size_t)node * 64 + c]);
            float hn = (1.f - gz) * ng + gz * ho;
            hb_out[(size_t)node * 64 + c] = f2bf(hn);
        }
    }
}

// ===================== MFMA decoder (R7) ===================================
__global__ __launch_bounds__(256) void k_decoder(
    const unsigned short* __restrict__ hb, const int* __restrict__ ei,
    const float* __restrict__ ea,
    const unsigned short* __restrict__ wd1f, const unsigned short* __restrict__ wd2f,
    const float* __restrict__ bd2,
    const float* __restrict__ Wd3, const float* __restrict__ bd3,
    float* __restrict__ out)
{
    __shared__ unsigned short d1f[4][1024];  // per-wave: 2 frags x 512
    __shared__ float d2s[4][16 * 33];        // per-wave: 16 edges x 32 (+pad)
    int tid = threadIdx.x, w = tid >> 6, lane = tid & 63;
    int l15 = lane & 15, quad = lane >> 4;
    int ebase = blockIdx.x * 64 + w * 16;
    int e = ebase + l15;
    int src = ei[e], dst = ei[N_EDGES + e];

    short8 a[5];
#pragma unroll
    for (int kb = 0; kb < 2; kb++) {
        a[kb]     = *(const short8*)(hb + (size_t)src * 64 + kb * 32 + quad * 8);
        a[2 + kb] = *(const short8*)(hb + (size_t)dst * 64 + kb * 32 + quad * 8);
    }
    {
        union { short8 v; unsigned short u[8]; } tea;
#pragma unroll
        for (int j = 0; j < 8; j++) {
            float vv = 0.f;
            if (quad == 0) vv = (j < 5) ? ea[(size_t)e * 5 + j] : (j == 5 ? 1.f : 0.f);
            tea.u[j] = f2bf(vv);
        }
        a[4] = tea.v;
    }

    float4v acc1[4] = {};
#pragma unroll
    for (int kb = 0; kb < 5; kb++)
#pragma unroll
        for (int nf = 0; nf < 4; nf++) {
            short8 b = *(const short8*)(wd1f + (size_t)((kb * 4 + nf) * 64 + lane) * 8);
            acc1[nf] = __builtin_amdgcn_mfma_f32_16x16x32_bf16(a[kb], b, acc1[nf], 0, 0, 0);
        }
#pragma unroll
    for (int nf = 0; nf < 4; nf++) {
        int kbp = nf >> 1;
        int lanep_hi = ((nf & 1) * 2 + (l15 >> 3)) * 16;
        int jp = l15 & 7;
#pragma unroll
        for (int r = 0; r < 4; r++) {
            float v = acc1[nf][r];
            d1f[w][kbp * 512 + (lanep_hi + quad * 4 + r) * 8 + jp] = f2bf(v > 0.f ? v : 0.f);
        }
    }
    float4v acc2[2] = {};
#pragma unroll
    for (int kb = 0; kb < 2; kb++) {
        short8 a2 = *(const short8*)(&d1f[w][kb * 512 + lane * 8]);
#pragma unroll
        for (int nf = 0; nf < 2; nf++) {
            short8 b = *(const short8*)(wd2f + (size_t)((kb * 2 + nf) * 64 + lane) * 8);
            acc2[nf] = __builtin_amdgcn_mfma_f32_16x16x32_bf16(a2, b, acc2[nf], 0, 0, 0);
        }
    }
#pragma unroll
    for (int nf = 0; nf < 2; nf++) {
        int c = nf * 16 + l15;
        float bias = bd2[c];
#pragma unroll
        for (int r = 0; r < 4; r++) {
            float v = acc2[nf][r] + bias;
            d2s[w][(quad * 4 + r) * 33 + c] = v > 0.f ? v : 0.f;
        }
    }
    {
        int e_l = lane >> 2, t = lane & 3;
        float s = bd3[t];
        const float* w3 = Wd3 + t * 32;
        const float* dr = &d2s[w][e_l * 33];
#pragma unroll
        for (int k = 0; k < 32; k++) s += w3[k] * dr[k];
        out[(size_t)(ebase + e_l) * 4 + t] = s;
    }
}

extern "C" void kernel_launch(void* const* d_in, const int* in_sizes, int n_in,
                              void* d_out, int out_size, void* d_ws, size_t ws_size,
                              hipStream_t stream)
{
    const float* x      = (const float*)d_in[0];
    const int*   ei     = (const int*)d_in[1];
    const float* ea     = (const float*)d_in[2];
    const float* u      = (const float*)d_in[3];
    const float* Wp     = (const float*)d_in[4];
    const float* bp     = (const float*)d_in[5];
    const float* We1    = (const float*)d_in[6];
    const float* be1    = (const float*)d_in[7];
    const float* We2    = (const float*)d_in[8];
    const float* be2    = (const float*)d_in[9];
    const float* root   = (const float*)d_in[10];
    const float* conv_b = (const float*)d_in[11];
    const float* Wih    = (const float*)d_in[12];
    const float* bih    = (const float*)d_in[13];
    const float* Whh    = (const float*)d_in[14];
    const float* bhh    = (const float*)d_in[15];
    const float* Wd1    = (const float*)d_in[16];
    const float* bd1    = (const float*)d_in[17];
    const float* Wd2    = (const float*)d_in[18];
    const float* bd2    = (const float*)d_in[19];
    const float* Wd3    = (const float*)d_in[20];
    const float* bd3    = (const float*)d_in[21];
    float* out = (float*)d_out;

    char* ws = (char*)d_ws;
    size_t off = 0;
    auto take = [&](size_t bytes) -> char* {
        char* p = ws + off; off = (off + bytes + 255) & ~(size_t)255; return p;
    };
    unsigned short* hb     = (unsigned short*)take((size_t)N_NODES * 64 * 2);
    unsigned short* hid    = (unsigned short*)take((size_t)N_EDGES * 64 * 2);
    float*          aggcnt = (float*)take((size_t)(N_NODES * 64 + N_NODES) * 4);
    float*          agg    = aggcnt;
    float*          cnts   = aggcnt + (size_t)N_NODES * 64;
    unsigned short* w2tf   = (unsigned short*)take((size_t)66 * 4096 * 2);  // +1 pad blk
    unsigned short* rootTf = (unsigned short*)take((size_t)4096 * 2);
    unsigned short* wcombf = (unsigned short*)take((size_t)32768 * 2);
    unsigned short* wd1f   = (unsigned short*)take((size_t)10240 * 2);
    unsigned short* wd2f   = (unsigned short*)take((size_t)2048 * 2);
    (void)ws_size;

    k_setup<<<19696, 256, 0, stream>>>(root, Wih, Whh, We2, be2, Wd1, bd1, Wd2,
                                       x, u, Wp, bp, ea, We1, be1,
                                       rootTf, wcombf, w2tf, wd1f, wd2f,
                                       hb, hid, aggcnt);
    k_counts<<<128, 256, 0, stream>>>(ei, cnts);

    for (int s = 0; s < STEPS; s++) {
        k_msg_fused<<<N_EDGES / 64, 256, 0, stream>>>(hid, hb, w2tf, ei, agg);
        k_node<<<N_NODES / 64, 256, 0, stream>>>(hb, rootTf, wcombf, agg, cnts,
                                                 conv_b, bih, bhh, hb);
    }
    k_decoder<<<N_EDGES / 64, 256, 0, stream>>>(hb, ei, ea, wd1f, wd2f, bd2,
                                                Wd3, bd3, out);
}

// Round 12
// 303.685 us; speedup vs baseline: 3.2304x; 1.0958x over previous
//
#include <hip/hip_runtime.h>
#include <hip/hip_bf16.h>
#include <stdint.h>

// MPNN latency predictor, MI355X — round 12.
// vs R11 (REGRESSED: 256-thr msg halved waves/CU 16->8, latency-exposed the
// staging drain): msg reverted to R7's exact 512-thr/8-wave/64-edge shape.
// NEW: whole pipeline bf16 -> fp16. Same MFMA rate, identical frag layouts,
// but A-generation becomes native packed v_pk_mul_f16 (4 VALU/frag vs ~12,
// no float round-hack) and fp16's 10-bit mantissa (vs bf16's 7) should DROP
// absmax ~4-8x. i-loop kept rolled (R9/R10 "container failed twice" was
// plausibly compile blowup of the unrolled body; R11 rolled compiled fine).

#define N_NODES 32768
#define N_EDGES 32768
#define STEPS 3

typedef __attribute__((ext_vector_type(8))) short short8;      // raw 16B loads
typedef __attribute__((ext_vector_type(8))) _Float16 half8;    // MFMA A/B frag
typedef __attribute__((ext_vector_type(2))) _Float16 half2v;   // packed pair
typedef __attribute__((ext_vector_type(4))) float float4v;     // MFMA C/D

__device__ __forceinline__ unsigned short f2h(float f) {  // RNE via v_cvt_f16_f32
    union { _Float16 h; unsigned short u; } c; c.h = (_Float16)f; return c.u;
}
__device__ __forceinline__ float h2f(unsigned short u) {
    union { unsigned short u; _Float16 h; } c; c.u = u; return (float)c.h;
}

// A-frag = hv2 (broadcast pair) * 8 packed h values: 4x v_pk_mul_f16
__device__ __forceinline__ half8 packA(half2v hv2, const half2v* hp) {
    union { half8 v; half2v h[4]; } r;
#pragma unroll
    for (int p = 0; p < 4; p++) r.h[p] = hv2 * hp[p];
    return r.v;
}

// async global->LDS, 16B/lane; lds dest = wave-uniform base + lane*16
__device__ __forceinline__ void gload_lds16(const void* g, void* l) {
    __builtin_amdgcn_global_load_lds(
        (__attribute__((address_space(1))) void*)g,
        (__attribute__((address_space(3))) void*)l, 16, 0, 0);
}

// ===================== fused setup kernel ==================================
// blockIdx segments (all weight tables frag-interleaved, fp16):
//  [0,144) rootTf+wcombf | [144,1184) w2tf | [1184,1232) wd1f+wd2f |
//  [1232,9424) proj | [9424,17616) edge hidden | [17616,19696) zero aggcnt
__global__ __launch_bounds__(256) void k_setup(
    const float* __restrict__ root, const float* __restrict__ Wih,
    const float* __restrict__ Whh,
    const float* __restrict__ We2, const float* __restrict__ be2,
    const float* __restrict__ Wd1, const float* __restrict__ bd1,
    const float* __restrict__ Wd2,
    const float* __restrict__ x, const float* __restrict__ u,
    const float* __restrict__ Wp, const float* __restrict__ bp,
    const float* __restrict__ ea, const float* __restrict__ We1,
    const float* __restrict__ be1,
    unsigned short* __restrict__ rootTf, unsigned short* __restrict__ wcombf,
    unsigned short* __restrict__ w2tf,
    unsigned short* __restrict__ wd1f, unsigned short* __restrict__ wd2f,
    unsigned short* __restrict__ hb,
    unsigned short* __restrict__ hid, float* __restrict__ aggcnt)
{
    int b = blockIdx.x, tid = threadIdx.x;
    if (b < 144) {
        int i = b * 256 + tid;
        if (i < 4096) {
            int j = i & 7, lane = (i >> 3) & 63, g = i >> 9;   // g<8
            int kb = g >> 2, nf = g & 3;
            int o = nf * 16 + (lane & 15);
            int k = kb * 32 + (lane >> 4) * 8 + j;
            rootTf[i] = f2h(root[k * 64 + o]);
        } else if (i < 4096 + 32768) {
            int t = i - 4096;
            int j = t & 7, lane = (t >> 3) & 63, g = t >> 9;   // g<64
            int kb = g >> 4, nf = g & 15;
            int cp = nf * 16 + (lane & 15);
            int k = kb * 32 + (lane >> 4) * 8 + j;
            float v;
            if (cp < 128)      v = (k < 64) ? Wih[cp * 64 + k] : Whh[cp * 64 + (k - 64)];
            else if (cp < 192) v = (k < 64) ? Wih[cp * 64 + k] : 0.f;
            else               v = (k < 64) ? 0.f : Whh[(cp - 64) * 64 + (k - 64)];
            wcombf[t] = f2h(v);
        }
    } else if (b < 1184) {
        int t = (b - 144) * 256 + tid;   // t < 266240
        if (t < 65 * 4096) {
            int kk = t >> 12, r = t & 4095;
            int j = r & 7, lane = (r >> 3) & 63, g = r >> 9;  // g<8
            int half = g >> 2, nf = g & 3;
            int o = nf * 16 + (lane & 15);
            int hh = half * 32 + (lane >> 4) * 8 + j;
            float v = (kk < 64) ? We2[((size_t)(hh * 64 + o)) * 64 + kk]
                                : be2[(size_t)hh * 64 + o];
            w2tf[t] = f2h(v);
        }
    } else if (b < 1232) {
        int i = (b - 1184) * 256 + tid;
        if (i < 10240) {
            int j = i & 7, lane = (i >> 3) & 63, g = i >> 9;  // g<20
            int kb = g >> 2, nf = g & 3;
            int o = nf * 16 + (lane & 15);
            int k = kb * 32 + (lane >> 4) * 8 + j;
            float v = (k < 133) ? Wd1[(size_t)o * 133 + k] : (k == 133 ? bd1[o] : 0.f);
            wd1f[i] = f2h(v);
        } else if (i < 10240 + 2048) {
            int t = i - 10240;
            int j = t & 7, lane = (t >> 3) & 63, g = t >> 9;  // g<4
            int kb = g >> 1, nf = g & 1;
            int o = nf * 16 + (lane & 15);
            int k = kb * 32 + (lane >> 4) * 8 + j;
            wd2f[t] = f2h(Wd2[(size_t)o * 64 + k]);
        }
    } else if (b < 9424) {
        int idx = (b - 1232) * 256 + tid;
        int n = idx >> 6, j = idx & 63;
        const float* wr = Wp + j * 23;
        const float* xr = x + (size_t)n * 12;
        float s = bp[j];
#pragma unroll
        for (int i = 0; i < 12; i++) s += xr[i] * wr[i];
#pragma unroll
        for (int i = 0; i < 11; i++) s += u[i] * wr[12 + i];
        hb[idx] = f2h(tanhf(s));
    } else if (b < 17616) {
        int idx = (b - 9424) * 256 + tid;
        int e = idx >> 6, j = idx & 63;
        float s = be1[j];
#pragma unroll
        for (int i = 0; i < 5; i++) s += ea[(size_t)e * 5 + i] * We1[j * 5 + i];
        hid[idx] = f2h(s > 0.f ? s : 0.f);
    } else {
        int idx = (b - 17616) * 1024 + tid * 4;
        if (idx < 2129920) {
            float4v z = {0.f, 0.f, 0.f, 0.f};
            *(float4v*)(aggcnt + idx) = z;
        }
    }
}

__global__ __launch_bounds__(256) void k_counts(
    const int* __restrict__ ei, float* __restrict__ counts)
{
    int i = blockIdx.x * 256 + threadIdx.x;
    if (i < N_EDGES) atomicAdd(&counts[ei[N_EDGES + i]], 1.0f);
}

// ===================== fused msg GEMM (R7 shape, fp16) =====================
// 512 threads = 8 waves: wave = kh*4 + mf (4 mf x 2 kh). 64 edges/block,
// kh0: kk 0..31, kh1: kk 32..64 (bias row, hid==1). Two kk per barrier: each
// kh stages a contiguous 16KB kk-pair (double-buffered, 64KB LDS, 2 blk/CU,
// 16 waves/CU). A-frags via v_pk_mul_f16. kh partials merged in LDS
// (stride-17, conflict-free); kh0 issues atomics.
__global__ __launch_bounds__(512, 4) void k_msg_fused(
    const unsigned short* __restrict__ hid,   // (E,64) fp16
    const unsigned short* __restrict__ hb,    // (N,64) fp16
    const unsigned short* __restrict__ w2tf,  // (66*4096) fp16 frag-interleaved
    const int* __restrict__ ei,
    float* __restrict__ agg)
{
    __shared__ unsigned short buf[2][2][8192];   // [kh][dbuf][16KB] = 64KB
    int tid = threadIdx.x, wave = tid >> 6, lane = tid & 63;
    int l15 = lane & 15, quad = lane >> 4;
    int mf = wave & 3, kh = wave >> 2;
    int ebase = blockIdx.x * 64 + mf * 16;
    int e_a = ebase + l15;
    int src = ei[e_a];

    // this kh-half's 32 hid values (fp16 bits) for this lane's edge
    union { short8 v[4]; unsigned short u[32]; } hrow;
#pragma unroll
    for (int i = 0; i < 4; i++)
        hrow.v[i] = *(const short8*)(hid + (size_t)e_a * 64 + kh * 32 + i * 8);

    // h[src] windows, kept packed fp16 (no float conversion)
    union Hp { half8 v; half2v p[4]; } hf0, hf1;
    hf0.v = *(const half8*)(hb + (size_t)src * 64 + quad * 8);
    hf1.v = *(const half8*)(hb + (size_t)src * 64 + 32 + quad * 8);

    int kk0 = kh ? 32 : 0;
    // stage kk-pair (16KB = 16 chunks of 1KB); wave mf stages chunks mf*4..+3
    auto stage = [&](int pair, int db) {
        const unsigned short* g = w2tf + (size_t)(kk0 + 2 * pair) * 4096;
#pragma unroll
        for (int c = 0; c < 4; c++) {
            int chunk = mf * 4 + c;
            gload_lds16(g + (size_t)chunk * 512 + lane * 8, &buf[kh][db][chunk * 512]);
        }
    };
    stage(0, 0);

    float4v acc[4] = {};
    int cur = 0;
    for (int i = 0; i <= 16; i++) {          // rolled (compile hedge)
        __syncthreads();   // staging of buf[*][cur] complete; prev reads done
        if ((kh == 0 && i + 1 < 16) || (kh == 1 && i + 1 <= 16))
            stage(i + 1, cur ^ 1);
        int nkk = (kh == 0) ? (i < 16 ? 2 : 0) : (i < 16 ? 2 : 1);  // wave-uniform
        for (int s = 0; s < nkk; s++) {
            const unsigned short* bp = &buf[kh][cur][s * 4096];
            unsigned short hu = (kh == 1 && i == 16) ? (unsigned short)0x3C00
                                                     : hrow.u[(2 * i + s) & 31];
            union { unsigned short u; _Float16 h; } cv; cv.u = hu;
            half2v hv2 = { cv.h, cv.h };
            half8 a0 = packA(hv2, hf0.p);
            half8 a1 = packA(hv2, hf1.p);
#pragma unroll
            for (int nf = 0; nf < 4; nf++) {
                half8 b0 = *(const half8*)(bp + (0 * 4 + nf) * 512 + lane * 8);
                acc[nf] = __builtin_amdgcn_mfma_f32_16x16x32_f16(a0, b0, acc[nf], 0, 0, 0);
            }
#pragma unroll
            for (int nf = 0; nf < 4; nf++) {
                half8 b1 = *(const half8*)(bp + (1 * 4 + nf) * 512 + lane * 8);
                acc[nf] = __builtin_amdgcn_mfma_f32_16x16x32_f16(a1, b1, acc[nf], 0, 0, 0);
            }
        }
        cur ^= 1;
    }

    // merge kh partials via LDS: row = mf*64+lane, stride 17 floats (odd ->
    // conflict-free). 256 rows x 17 x 4B = 17.4KB inside buf.
    __syncthreads();
    float* mg = (float*)&buf[0][0][0];
    if (kh == 1) {
#pragma unroll
        for (int nf = 0; nf < 4; nf++)
#pragma unroll
            for (int r = 0; r < 4; r++)
                mg[(mf * 64 + lane) * 17 + nf * 4 + r] = acc[nf][r];
    }
    __syncthreads();
    if (kh == 0) {
        int dsts[4];
#pragma unroll
        for (int r = 0; r < 4; r++) dsts[r] = ei[N_EDGES + ebase + quad * 4 + r];
#pragma unroll
        for (int nf = 0; nf < 4; nf++)
#pragma unroll
            for (int r = 0; r < 4; r++)
                atomicAdd(agg + (size_t)dsts[r] * 64 + nf * 16 + l15,
                          acc[nf][r] + mg[(mf * 64 + lane) * 17 + nf * 4 + r]);
    }
}

// ===================== fused node update (fp16) ============================
__global__ __launch_bounds__(256) void k_node(
    const unsigned short* __restrict__ hb_in,
    const unsigned short* __restrict__ rootTf,
    const unsigned short* __restrict__ wcombf,
    float* __restrict__ agg, const float* __restrict__ counts,
    const float* __restrict__ conv_b,
    const float* __restrict__ bih, const float* __restrict__ bhh,
    unsigned short* __restrict__ hb_out)
{
    __shared__ unsigned short m_lds[64 * 72];
    int tid = threadIdx.x, w = tid >> 6, lane = tid & 63;
    int l15 = lane & 15, quad = lane >> 4;
    int node0 = blockIdx.x * 64;
    int row0 = w * 16;

    float4v acc1[4] = {};
    {
        half8 a1[2];
#pragma unroll
        for (int kb = 0; kb < 2; kb++)
            a1[kb] = *(const half8*)(hb_in + (size_t)(node0 + row0 + l15) * 64 + kb * 32 + quad * 8);
#pragma unroll
        for (int kb = 0; kb < 2; kb++)
#pragma unroll
            for (int nf = 0; nf < 4; nf++) {
                half8 b = *(const half8*)(rootTf + (size_t)((kb * 4 + nf) * 64 + lane) * 8);
                acc1[nf] = __builtin_amdgcn_mfma_f32_16x16x32_f16(a1[kb], b, acc1[nf], 0, 0, 0);
            }
    }
#pragma unroll
    for (int rr = 0; rr < 4; rr++) {
        int nl = row0 + quad * 4 + rr;
        float cnt = counts[node0 + nl]; if (cnt < 1.f) cnt = 1.f;
        float rcp = 1.f / cnt;
#pragma unroll
        for (int nf = 0; nf < 4; nf++) {
            int c = nf * 16 + l15;
            float* ap = agg + (size_t)(node0 + nl) * 64 + c;
            float av = *ap;
            *ap = 0.f;
            float mv = av * rcp + acc1[nf][rr] + conv_b[c];
            m_lds[nl * 72 + c] = f2h(mv > 0.f ? mv : 0.f);
        }
    }
    __syncthreads();

    float4v acc2[16] = {};
#pragma unroll
    for (int kb = 0; kb < 4; kb++) {
        half8 a2;
        if (kb < 2)
            a2 = *(const half8*)(m_lds + (row0 + l15) * 72 + kb * 32 + quad * 8);
        else
            a2 = *(const half8*)(hb_in + (size_t)(node0 + row0 + l15) * 64 + (kb - 2) * 32 + quad * 8);
#pragma unroll
        for (int nf = 0; nf < 16; nf++) {
            half8 b = *(const half8*)(wcombf + (size_t)((kb * 16 + nf) * 64 + lane) * 8);
            acc2[nf] = __builtin_amdgcn_mfma_f32_16x16x32_f16(a2, b, acc2[nf], 0, 0, 0);
        }
    }

#pragma unroll
    for (int nf0 = 0; nf0 < 4; nf0++) {
        int c = nf0 * 16 + l15;
        float br = bih[c] + bhh[c];
        float bz = bih[64 + c] + bhh[64 + c];
        float bni = bih[128 + c], bnh = bhh[128 + c];
#pragma unroll
        for (int rr = 0; rr < 4; rr++) {
            int node = node0 + row0 + quad * 4 + rr;
            float gr = 1.f / (1.f + __expf(-(acc2[nf0][rr] + br)));
            float gz = 1.f / (1.f + __expf(-(acc2[nf0 + 4][rr] + bz)));
            float ng = tanhf(acc2[nf0 + 8][rr] + bni + gr * (acc2[nf0 + 12][rr] + bnh));
            float ho = h2f(hb_in[(size_t)node * 64 + c]);
            float hn = (1.f - gz) * ng + gz * ho;
            hb_out[(size_t)node * 64 + c] = f2h(hn);
        }
    }
}

// ===================== MFMA decoder (fp16) =================================
__global__ __launch_bounds__(256) void k_decoder(
    const unsigned short* __restrict__ hb, const int* __restrict__ ei,
    const float* __restrict__ ea,
    const unsigned short* __restrict__ wd1f, const unsigned short* __restrict__ wd2f,
    const float* __restrict__ bd2,
    const float* __restrict__ Wd3, const float* __restrict__ bd3,
    float* __restrict__ out)
{
    __shared__ unsigned short d1f[4][1024];  // per-wave: 2 frags x 512
    __shared__ float d2s[4][16 * 33];        // per-wave: 16 edges x 32 (+pad)
    int tid = threadIdx.x, w = tid >> 6, lane = tid & 63;
    int l15 = lane & 15, quad = lane >> 4;
    int ebase = blockIdx.x * 64 + w * 16;
    int e = ebase + l15;
    int src = ei[e], dst = ei[N_EDGES + e];

    half8 a[5];
#pragma unroll
    for (int kb = 0; kb < 2; kb++) {
        a[kb]     = *(const half8*)(hb + (size_t)src * 64 + kb * 32 + quad * 8);
        a[2 + kb] = *(const half8*)(hb + (size_t)dst * 64 + kb * 32 + quad * 8);
    }
    {
        union { half8 v; unsigned short u[8]; } tea;
#pragma unroll
        for (int j = 0; j < 8; j++) {
            float vv = 0.f;
            if (quad == 0) vv = (j < 5) ? ea[(size_t)e * 5 + j] : (j == 5 ? 1.f : 0.f);
            tea.u[j] = f2h(vv);
        }
        a[4] = tea.v;
    }

    float4v acc1[4] = {};
#pragma unroll
    for (int kb = 0; kb < 5; kb++)
#pragma unroll
        for (int nf = 0; nf < 4; nf++) {
            half8 b = *(const half8*)(wd1f + (size_t)((kb * 4 + nf) * 64 + lane) * 8);
            acc1[nf] = __builtin_amdgcn_mfma_f32_16x16x32_f16(a[kb], b, acc1[nf], 0, 0, 0);
        }
#pragma unroll
    for (int nf = 0; nf < 4; nf++) {
        int kbp = nf >> 1;
        int lanep_hi = ((nf & 1) * 2 + (l15 >> 3)) * 16;
        int jp = l15 & 7;
#pragma unroll
        for (int r = 0; r < 4; r++) {
            float v = acc1[nf][r];
            d1f[w][kbp * 512 + (lanep_hi + quad * 4 + r) * 8 + jp] = f2h(v > 0.f ? v : 0.f);
        }
    }
    float4v acc2[2] = {};
#pragma unroll
    for (int kb = 0; kb < 2; kb++) {
        half8 a2 = *(const half8*)(&d1f[w][kb * 512 + lane * 8]);
#pragma unroll
        for (int nf = 0; nf < 2; nf++) {
            half8 b = *(const half8*)(wd2f + (size_t)((kb * 2 + nf) * 64 + lane) * 8);
            acc2[nf] = __builtin_amdgcn_mfma_f32_16x16x32_f16(a2, b, acc2[nf], 0, 0, 0);
        }
    }
#pragma unroll
    for (int nf = 0; nf < 2; nf++) {
        int c = nf * 16 + l15;
        float bias = bd2[c];
#pragma unroll
        for (int r = 0; r < 4; r++) {
            float v = acc2[nf][r] + bias;
            d2s[w][(quad * 4 + r) * 33 + c] = v > 0.f ? v : 0.f;
        }
    }
    {
        int e_l = lane >> 2, t = lane & 3;
        float s = bd3[t];
        const float* w3 = Wd3 + t * 32;
        const float* dr = &d2s[w][e_l * 33];
#pragma unroll
        for (int k = 0; k < 32; k++) s += w3[k] * dr[k];
        out[(size_t)(ebase + e_l) * 4 + t] = s;
    }
}

extern "C" void kernel_launch(void* const* d_in, const int* in_sizes, int n_in,
                              void* d_out, int out_size, void* d_ws, size_t ws_size,
                              hipStream_t stream)
{
    const float* x      = (const float*)d_in[0];
    const int*   ei     = (const int*)d_in[1];
    const float* ea     = (const float*)d_in[2];
    const float* u      = (const float*)d_in[3];
    const float* Wp     = (const float*)d_in[4];
    const float* bp     = (const float*)d_in[5];
    const float* We1    = (const float*)d_in[6];
    const float* be1    = (const float*)d_in[7];
    const float* We2    = (const float*)d_in[8];
    const float* be2    = (const float*)d_in[9];
    const float* root   = (const float*)d_in[10];
    const float* conv_b = (const float*)d_in[11];
    const float* Wih    = (const float*)d_in[12];
    const float* bih    = (const float*)d_in[13];
    const float* Whh    = (const float*)d_in[14];
    const float* bhh    = (const float*)d_in[15];
    const float* Wd1    = (const float*)d_in[16];
    const float* bd1    = (const float*)d_in[17];
    const float* Wd2    = (const float*)d_in[18];
    const float* bd2    = (const float*)d_in[19];
    const float* Wd3    = (const float*)d_in[20];
    const float* bd3    = (const float*)d_in[21];
    float* out = (float*)d_out;

    char* ws = (char*)d_ws;
    size_t off = 0;
    auto take = [&](size_t bytes) -> char* {
        char* p = ws + off; off = (off + bytes + 255) & ~(size_t)255; return p;
    };
    unsigned short* hb     = (unsigned short*)take((size_t)N_NODES * 64 * 2);
    unsigned short* hid    = (unsigned short*)take((size_t)N_EDGES * 64 * 2);
    float*          aggcnt = (float*)take((size_t)(N_NODES * 64 + N_NODES) * 4);
    float*          agg    = aggcnt;
    float*          cnts   = aggcnt + (size_t)N_NODES * 64;
    unsigned short* w2tf   = (unsigned short*)take((size_t)66 * 4096 * 2);  // +1 pad blk
    unsigned short* rootTf = (unsigned short*)take((size_t)4096 * 2);
    unsigned short* wcombf = (unsigned short*)take((size_t)32768 * 2);
    unsigned short* wd1f   = (unsigned short*)take((size_t)10240 * 2);
    unsigned short* wd2f   = (unsigned short*)take((size_t)2048 * 2);
    (void)ws_size;

    k_setup<<<19696, 256, 0, stream>>>(root, Wih, Whh, We2, be2, Wd1, bd1, Wd2,
                                       x, u, Wp, bp, ea, We1, be1,
                                       rootTf, wcombf, w2tf, wd1f, wd2f,
                                       hb, hid, aggcnt);
    k_counts<<<128, 256, 0, stream>>>(ei, cnts);

    for (int s = 0; s < STEPS; s++) {
        k_msg_fused<<<N_EDGES / 64, 512, 0, stream>>>(hid, hb, w2tf, ei, agg);
        k_node<<<N_NODES / 64, 256, 0, stream>>>(hb, rootTf, wcombf, agg, cnts,
                                                 conv_b, bih, bhh, hb);
    }
    k_decoder<<<N_EDGES / 64, 256, 0, stream>>>(hb, ei, ea, wd1f, wd2f, bd2,
                                                Wd3, bd3, out);
}

// Round 15
// 268.061 us; speedup vs baseline: 3.6597x; 1.1329x over previous
//
#include <hip/hip_runtime.h>
#include <hip/hip_bf16.h>
#include <stdint.h>

// MPNN latency predictor, MI355X — round 15.
// RE-ANCHOR: this is the R7 source (267us, proven compile+run) byte-identical
// except ONE micro-fix: kh-merge LDS layout stride 16 -> 17 floats/row (odd
// stride = bank-conflict-free; R8 counters showed ~1M conflict cycles on the
// stride-16 pattern). Rationale: R9/R10/R13/R14 all died with "container
// failed twice" while R11/R12 ran — failures cluster in consecutive-round
// windows, so infra-vs-source is ambiguous; submitting a proven-compilable
// source is the control that disambiguates.

#define N_NODES 32768
#define N_EDGES 32768
#define STEPS 3

typedef __attribute__((ext_vector_type(8))) short short8;   // 8 bf16 = 4 VGPRs
typedef __attribute__((ext_vector_type(4))) float float4v;  // MFMA C/D

__device__ __forceinline__ float bf2f(unsigned short u) {
    union { unsigned int i; float f; } v; v.i = ((unsigned int)u) << 16; return v.f;
}
__device__ __forceinline__ unsigned short f2bf(float f) {  // RNE
    union { float f; unsigned int i; } v; v.f = f;
    unsigned int x = v.i;
    return (unsigned short)((x + 0x7fffu + ((x >> 16) & 1u)) >> 16);
}
__device__ __forceinline__ unsigned int fbits(float f) {
    union { float f; unsigned int i; } v; v.f = f; return v.i;
}

// pack 8 products hv*hf[j] into a bf16x8 A-frag: round-half-up + v_perm pack
__device__ __forceinline__ short8 packA(float hv, const float* hf) {
    union { short8 v; unsigned int u[4]; } r;
#pragma unroll
    for (int p = 0; p < 4; p++) {
        unsigned int p0 = fbits(hv * hf[2 * p]) + 0x8000u;
        unsigned int p1 = fbits(hv * hf[2 * p + 1]) + 0x8000u;
        r.u[p] = __builtin_amdgcn_perm(p1, p0, 0x07060302u);  // {hi16(p0), hi16(p1)}
    }
    return r.v;
}

// async global->LDS, 16B/lane; lds dest = wave-uniform base + lane*16
__device__ __forceinline__ void gload_lds16(const void* g, void* l) {
    __builtin_amdgcn_global_load_lds(
        (__attribute__((address_space(1))) void*)g,
        (__attribute__((address_space(3))) void*)l, 16, 0, 0);
}

// ===================== fused setup kernel ==================================
// blockIdx segments:
//  [0,144)       rootTf (4096) + wcombf (32768)      — frag-interleaved
//  [144,1184)    w2tf (266240 valid + 4096 pad)       — frag-interleaved
//  [1184,1232)   wd1f (10240) + wd2f (2048)           — frag-interleaved
//  [1232,9424)   proj: hb = bf16(tanh([x,u]@Wp^T+bp))
//  [9424,17616)  edge hidden: hid = relu(ea@We1^T+be1)
//  [17616,19696) zero aggcnt (2129920 floats, float4 stores)
__global__ __launch_bounds__(256) void k_setup(
    const float* __restrict__ root, const float* __restrict__ Wih,
    const float* __restrict__ Whh,
    const float* __restrict__ We2, const float* __restrict__ be2,
    const float* __restrict__ Wd1, const float* __restrict__ bd1,
    const float* __restrict__ Wd2,
    const float* __restrict__ x, const float* __restrict__ u,
    const float* __restrict__ Wp, const float* __restrict__ bp,
    const float* __restrict__ ea, const float* __restrict__ We1,
    const float* __restrict__ be1,
    unsigned short* __restrict__ rootTf, unsigned short* __restrict__ wcombf,
    unsigned short* __restrict__ w2tf,
    unsigned short* __restrict__ wd1f, unsigned short* __restrict__ wd2f,
    unsigned short* __restrict__ hb,
    unsigned short* __restrict__ hid, float* __restrict__ aggcnt)
{
    int b = blockIdx.x, tid = threadIdx.x;
    if (b < 144) {
        int i = b * 256 + tid;
        if (i < 4096) {
            int j = i & 7, lane = (i >> 3) & 63, g = i >> 9;   // g<8
            int kb = g >> 2, nf = g & 3;
            int o = nf * 16 + (lane & 15);
            int k = kb * 32 + (lane >> 4) * 8 + j;
            rootTf[i] = f2bf(root[k * 64 + o]);
        } else if (i < 4096 + 32768) {
            int t = i - 4096;
            int j = t & 7, lane = (t >> 3) & 63, g = t >> 9;   // g<64
            int kb = g >> 4, nf = g & 15;
            int cp = nf * 16 + (lane & 15);
            int k = kb * 32 + (lane >> 4) * 8 + j;
            float v;
            if (cp < 128)      v = (k < 64) ? Wih[cp * 64 + k] : Whh[cp * 64 + (k - 64)];
            else if (cp < 192) v = (k < 64) ? Wih[cp * 64 + k] : 0.f;
            else               v = (k < 64) ? 0.f : Whh[(cp - 64) * 64 + (k - 64)];
            wcombf[t] = f2bf(v);
        }
    } else if (b < 1184) {
        int t = (b - 144) * 256 + tid;   // t < 266240
        if (t < 65 * 4096) {
            int kk = t >> 12, r = t & 4095;
            int j = r & 7, lane = (r >> 3) & 63, g = r >> 9;  // g<8
            int half = g >> 2, nf = g & 3;
            int o = nf * 16 + (lane & 15);
            int hh = half * 32 + (lane >> 4) * 8 + j;
            float v = (kk < 64) ? We2[((size_t)(hh * 64 + o)) * 64 + kk]
                                : be2[(size_t)hh * 64 + o];
            w2tf[t] = f2bf(v);
        }
    } else if (b < 1232) {
        int i = (b - 1184) * 256 + tid;
        if (i < 10240) {
            int j = i & 7, lane = (i >> 3) & 63, g = i >> 9;  // g<20
            int kb = g >> 2, nf = g & 3;
            int o = nf * 16 + (lane & 15);
            int k = kb * 32 + (lane >> 4) * 8 + j;
            float v = (k < 133) ? Wd1[(size_t)o * 133 + k] : (k == 133 ? bd1[o] : 0.f);
            wd1f[i] = f2bf(v);
        } else if (i < 10240 + 2048) {
            int t = i - 10240;
            int j = t & 7, lane = (t >> 3) & 63, g = t >> 9;  // g<4
            int kb = g >> 1, nf = g & 1;
            int o = nf * 16 + (lane & 15);
            int k = kb * 32 + (lane >> 4) * 8 + j;
            wd2f[t] = f2bf(Wd2[(size_t)o * 64 + k]);
        }
    } else if (b < 9424) {
        int idx = (b - 1232) * 256 + tid;
        int n = idx >> 6, j = idx & 63;
        const float* wr = Wp + j * 23;
        const float* xr = x + (size_t)n * 12;
        float s = bp[j];
#pragma unroll
        for (int i = 0; i < 12; i++) s += xr[i] * wr[i];
#pragma unroll
        for (int i = 0; i < 11; i++) s += u[i] * wr[12 + i];
        hb[idx] = f2bf(tanhf(s));
    } else if (b < 17616) {
        int idx = (b - 9424) * 256 + tid;
        int e = idx >> 6, j = idx & 63;
        float s = be1[j];
#pragma unroll
        for (int i = 0; i < 5; i++) s += ea[(size_t)e * 5 + i] * We1[j * 5 + i];
        hid[idx] = f2bf(s > 0.f ? s : 0.f);
    } else {
        int idx = (b - 17616) * 1024 + tid * 4;
        if (idx < 2129920) {
            float4v z = {0.f, 0.f, 0.f, 0.f};
            *(float4v*)(aggcnt + idx) = z;
        }
    }
}

__global__ __launch_bounds__(256) void k_counts(
    const int* __restrict__ ei, float* __restrict__ counts)
{
    int i = blockIdx.x * 256 + threadIdx.x;
    if (i < N_EDGES) atomicAdd(&counts[ei[N_EDGES + i]], 1.0f);
}

// ===================== fused msg GEMM ======================================
// 512 threads = 8 waves: wave = kh*4 + mf. 64 edges/block, kh picks K-half
// (kh0: kk 0..31, kh1: kk 32..64 incl bias row). TWO kk per barrier: each kh
// stages a contiguous 16KB kk-pair (double-buffered; 64KB LDS total) shared
// by its 4 mf-waves. 17 barriers. kh partials merged in LDS (stride-17 rows,
// conflict-free — the only change vs the 267us R7 source); kh0 atomics.
__global__ __launch_bounds__(512, 4) void k_msg_fused(
    const unsigned short* __restrict__ hid,   // (E,64) bf16
    const unsigned short* __restrict__ hb,    // (N,64) bf16
    const unsigned short* __restrict__ w2tf,  // (66*4096) frag-interleaved
    const int* __restrict__ ei,
    float* __restrict__ agg)
{
    __shared__ unsigned short buf[2][2][8192];   // [kh][dbuf][2 kk x 4096] 64KB
    int tid = threadIdx.x, wave = tid >> 6, lane = tid & 63;
    int l15 = lane & 15, quad = lane >> 4;
    int mf = wave & 3, kh = wave >> 2;
    int ebase = blockIdx.x * 64 + mf * 16;
    int e_a = ebase + l15;
    int src = ei[e_a];

    // this kh-half's 32 hid values for this lane's edge
    union { short8 v[4]; unsigned short u[32]; } hrow;
#pragma unroll
    for (int i = 0; i < 4; i++)
        hrow.v[i] = *(const short8*)(hid + (size_t)e_a * 64 + kh * 32 + i * 8);

    float hf0[8], hf1[8];
    {
        short8 h0 = *(const short8*)(hb + (size_t)src * 64 + quad * 8);
        short8 h1 = *(const short8*)(hb + (size_t)src * 64 + 32 + quad * 8);
#pragma unroll
        for (int j = 0; j < 8; j++) {
            hf0[j] = bf2f((unsigned short)h0[j]);
            hf1[j] = bf2f((unsigned short)h1[j]);
        }
    }

    int kk0 = kh ? 32 : 0;
    // stage kk-pair `pair` (16KB contiguous: kks kk0+2p, kk0+2p+1) into
    // buf[kh][db]; wave mf stages chunks mf*4 .. mf*4+3 (1KB each)
    auto stage = [&](int pair, int db) {
        const unsigned short* g = w2tf + (size_t)(kk0 + 2 * pair) * 4096;
#pragma unroll
        for (int c = 0; c < 4; c++) {
            int chunk = mf * 4 + c;
            gload_lds16(g + (size_t)chunk * 512 + lane * 8, &buf[kh][db][chunk * 512]);
        }
    };

    stage(0, 0);

    float4v acc[4] = {};
    int cur = 0;
#pragma unroll
    for (int i = 0; i <= 16; i++) {
        __syncthreads();   // staging of buf[*][cur] complete; prev reads done
        if ((kh == 0 && i + 1 < 16) || (kh == 1 && i + 1 <= 16))
            stage(i + 1, cur ^ 1);
        int nkk = (kh == 0) ? (i < 16 ? 2 : 0) : (i < 16 ? 2 : 1);  // wave-uniform
        for (int s = 0; s < nkk; s++) {
            float hv = (kh == 1 && i == 16) ? 1.0f : bf2f(hrow.u[(2 * i + s) & 31]);
            short8 a0 = packA(hv, hf0);
            short8 a1 = packA(hv, hf1);
            const unsigned short* bp = &buf[kh][cur][s * 4096];
#pragma unroll
            for (int nf = 0; nf < 4; nf++) {
                short8 b0 = *(const short8*)(bp + (0 * 4 + nf) * 512 + lane * 8);
                acc[nf] = __builtin_amdgcn_mfma_f32_16x16x32_bf16(a0, b0, acc[nf], 0, 0, 0);
            }
#pragma unroll
            for (int nf = 0; nf < 4; nf++) {
                short8 b1 = *(const short8*)(bp + (1 * 4 + nf) * 512 + lane * 8);
                acc[nf] = __builtin_amdgcn_mfma_f32_16x16x32_bf16(a1, b1, acc[nf], 0, 0, 0);
            }
        }
        cur ^= 1;
    }

    // merge kh partials via LDS: row = mf*64+lane, stride 17 floats (odd ->
    // conflict-free). 256 rows x 17 x 4B = 17.4KB inside buf.
    __syncthreads();
    float* mg = (float*)&buf[0][0][0];
    if (kh == 1) {
#pragma unroll
        for (int nf = 0; nf < 4; nf++)
#pragma unroll
            for (int r = 0; r < 4; r++)
                mg[(mf * 64 + lane) * 17 + nf * 4 + r] = acc[nf][r];
    }
    __syncthreads();
    if (kh == 0) {
        int dsts[4];
#pragma unroll
        for (int r = 0; r < 4; r++) dsts[r] = ei[N_EDGES + ebase + quad * 4 + r];
#pragma unroll
        for (int nf = 0; nf < 4; nf++)
#pragma unroll
            for (int r = 0; r < 4; r++)
                atomicAdd(agg + (size_t)dsts[r] * 64 + nf * 16 + l15,
                          acc[nf][r] + mg[(mf * 64 + lane) * 17 + nf * 4 + r]);
    }
}

// ===================== fused node update ===================================
__global__ __launch_bounds__(256) void k_node(
    const unsigned short* __restrict__ hb_in,
    const unsigned short* __restrict__ rootTf,
    const unsigned short* __restrict__ wcombf,
    float* __restrict__ agg, const float* __restrict__ counts,
    const float* __restrict__ conv_b,
    const float* __restrict__ bih, const float* __restrict__ bhh,
    unsigned short* __restrict__ hb_out)
{
    __shared__ unsigned short m_lds[64 * 72];
    int tid = threadIdx.x, w = tid >> 6, lane = tid & 63;
    int l15 = lane & 15, quad = lane >> 4;
    int node0 = blockIdx.x * 64;
    int row0 = w * 16;

    float4v acc1[4] = {};
    {
        short8 a1[2];
#pragma unroll
        for (int kb = 0; kb < 2; kb++)
            a1[kb] = *(const short8*)(hb_in + (size_t)(node0 + row0 + l15) * 64 + kb * 32 + quad * 8);
#pragma unroll
        for (int kb = 0; kb < 2; kb++)
#pragma unroll
            for (int nf = 0; nf < 4; nf++) {
                short8 b = *(const short8*)(rootTf + (size_t)((kb * 4 + nf) * 64 + lane) * 8);
                acc1[nf] = __builtin_amdgcn_mfma_f32_16x16x32_bf16(a1[kb], b, acc1[nf], 0, 0, 0);
            }
    }
#pragma unroll
    for (int rr = 0; rr < 4; rr++) {
        int nl = row0 + quad * 4 + rr;
        float cnt = counts[node0 + nl]; if (cnt < 1.f) cnt = 1.f;
        float rcp = 1.f / cnt;
#pragma unroll
        for (int nf = 0; nf < 4; nf++) {
            int c = nf * 16 + l15;
            float* ap = agg + (size_t)(node0 + nl) * 64 + c;
            float av = *ap;
            *ap = 0.f;
            float mv = av * rcp + acc1[nf][rr] + conv_b[c];
            m_lds[nl * 72 + c] = f2bf(mv > 0.f ? mv : 0.f);
        }
    }
    __syncthreads();

    float4v acc2[16] = {};
#pragma unroll
    for (int kb = 0; kb < 4; kb++) {
        short8 a2;
        if (kb < 2)
            a2 = *(const short8*)(m_lds + (row0 + l15) * 72 + kb * 32 + quad * 8);
        else
            a2 = *(const short8*)(hb_in + (size_t)(node0 + row0 + l15) * 64 + (kb - 2) * 32 + quad * 8);
#pragma unroll
        for (int nf = 0; nf < 16; nf++) {
            short8 b = *(const short8*)(wcombf + (size_t)((kb * 16 + nf) * 64 + lane) * 8);
            acc2[nf] = __builtin_amdgcn_mfma_f32_16x16x32_bf16(a2, b, acc2[nf], 0, 0, 0);
        }
    }

#pragma unroll
    for (int nf0 = 0; nf0 < 4; nf0++) {
        int c = nf0 * 16 + l15;
        float br = bih[c] + bhh[c];
        float bz = bih[64 + c] + bhh[64 + c];
        float bni = bih[128 + c], bnh = bhh[128 + c];
#pragma unroll
        for (int rr = 0; rr < 4; rr++) {
            int node = node0 + row0 + quad * 4 + rr;
            float gr = 1.f / (1.f + __expf(-(acc2[nf0][rr] + br)));
            float gz = 1.f / (1.f + __expf(-(acc2[nf0 + 4][rr] + bz)));
            float ng = tanhf(acc2[nf0 + 8][rr] + bni + gr * (acc2[nf0 + 12][rr] + bnh));
            float ho = bf2f(hb_in[(size_t)node * 64 + c]);
            float hn = (1.f - gz) * ng + gz * ho;
            hb_out[(size_t)node * 64 + c] = f2bf(hn);
        }
    }
}

// ===================== MFMA decoder ========================================
__global__ __launch_bounds__(256) void k_decoder(
    const unsigned short* __restrict__ hb, const int* __restrict__ ei,
    const float* __restrict__ ea,
    const unsigned short* __restrict__ wd1f, const unsigned short* __restrict__ wd2f,
    const float* __restrict__ bd2,
    const float* __restrict__ Wd3, const float* __restrict__ bd3,
    float* __restrict__ out)
{
    __shared__ unsigned short d1f[4][1024];  // per-wave: 2 frags x 512
    __shared__ float d2s[4][16 * 33];        // per-wave: 16 edges x 32 (+pad)
    int tid = threadIdx.x, w = tid >> 6, lane = tid & 63;
    int l15 = lane & 15, quad = lane >> 4;
    int ebase = blockIdx.x * 64 + w * 16;
    int e = ebase + l15;
    int src = ei[e], dst = ei[N_EDGES + e];

    short8 a[5];
#pragma unroll
    for (int kb = 0; kb < 2; kb++) {
        a[kb]     = *(const short8*)(hb + (size_t)src * 64 + kb * 32 + quad * 8);
        a[2 + kb] = *(const short8*)(hb + (size_t)dst * 64 + kb * 32 + quad * 8);
    }
    {
        union { short8 v; unsigned short u[8]; } tea;
#pragma unroll
        for (int j = 0; j < 8; j++) {
            float vv = 0.f;
            if (quad == 0) vv = (j < 5) ? ea[(size_t)e * 5 + j] : (j == 5 ? 1.f : 0.f);
            tea.u[j] = f2bf(vv);
        }
        a[4] = tea.v;
    }

    float4v acc1[4] = {};
#pragma unroll
    for (int kb = 0; kb < 5; kb++)
#pragma unroll
        for (int nf = 0; nf < 4; nf++) {
            short8 b = *(const short8*)(wd1f + (size_t)((kb * 4 + nf) * 64 + lane) * 8);
            acc1[nf] = __builtin_amdgcn_mfma_f32_16x16x32_bf16(a[kb], b, acc1[nf], 0, 0, 0);
        }
#pragma unroll
    for (int nf = 0; nf < 4; nf++) {
        int kbp = nf >> 1;
        int lanep_hi = ((nf & 1) * 2 + (l15 >> 3)) * 16;
        int jp = l15 & 7;
#pragma unroll
        for (int r = 0; r < 4; r++) {
            float v = acc1[nf][r];
            d1f[w][kbp * 512 + (lanep_hi + quad * 4 + r) * 8 + jp] = f2bf(v > 0.f ? v : 0.f);
        }
    }
    float4v acc2[2] = {};
#pragma unroll
    for (int kb = 0; kb < 2; kb++) {
        short8 a2 = *(const short8*)(&d1f[w][kb * 512 + lane * 8]);
#pragma unroll
        for (int nf = 0; nf < 2; nf++) {
            short8 b = *(const short8*)(wd2f + (size_t)((kb * 2 + nf) * 64 + lane) * 8);
            acc2[nf] = __builtin_amdgcn_mfma_f32_16x16x32_bf16(a2, b, acc2[nf], 0, 0, 0);
        }
    }
#pragma unroll
    for (int nf = 0; nf < 2; nf++) {
        int c = nf * 16 + l15;
        float bias = bd2[c];
#pragma unroll
        for (int r = 0; r < 4; r++) {
            float v = acc2[nf][r] + bias;
            d2s[w][(quad * 4 + r) * 33 + c] = v > 0.f ? v : 0.f;
        }
    }
    {
        int e_l = lane >> 2, t = lane & 3;
        float s = bd3[t];
        const float* w3 = Wd3 + t * 32;
        const float* dr = &d2s[w][e_l * 33];
#pragma unroll
        for (int k = 0; k < 32; k++) s += w3[k] * dr[k];
        out[(size_t)(ebase + e_l) * 4 + t] = s;
    }
}

extern "C" void kernel_launch(void* const* d_in, const int* in_sizes, int n_in,
                              void* d_out, int out_size, void* d_ws, size_t ws_size,
                              hipStream_t stream)
{
    const float* x      = (const float*)d_in[0];
    const int*   ei     = (const int*)d_in[1];
    const float* ea     = (const float*)d_in[2];
    const float* u      = (const float*)d_in[3];
    const float* Wp     = (const float*)d_in[4];
    const float* bp     = (const float*)d_in[5];
    const float* We1    = (const float*)d_in[6];
    const float* be1    = (const float*)d_in[7];
    const float* We2    = (const float*)d_in[8];
    const float* be2    = (const float*)d_in[9];
    const float* root   = (const float*)d_in[10];
    const float* conv_b = (const float*)d_in[11];
    const float* Wih    = (const float*)d_in[12];
    const float* bih    = (const float*)d_in[13];
    const float* Whh    = (const float*)d_in[14];
    const float* bhh    = (const float*)d_in[15];
    const float* Wd1    = (const float*)d_in[16];
    const float* bd1    = (const float*)d_in[17];
    const float* Wd2    = (const float*)d_in[18];
    const float* bd2    = (const float*)d_in[19];
    const float* Wd3    = (const float*)d_in[20];
    const float* bd3    = (const float*)d_in[21];
    float* out = (float*)d_out;

    char* ws = (char*)d_ws;
    size_t off = 0;
    auto take = [&](size_t bytes) -> char* {
        char* p = ws + off; off = (off + bytes + 255) & ~(size_t)255; return p;
    };
    unsigned short* hb     = (unsigned short*)take((size_t)N_NODES * 64 * 2);
    unsigned short* hid    = (unsigned short*)take((size_t)N_EDGES * 64 * 2);
    float*          aggcnt = (float*)take((size_t)(N_NODES * 64 + N_NODES) * 4);
    float*          agg    = aggcnt;
    float*          cnts   = aggcnt + (size_t)N_NODES * 64;
    unsigned short* w2tf   = (unsigned short*)take((size_t)66 * 4096 * 2);  // +1 pad blk
    unsigned short* rootTf = (unsigned short*)take((size_t)4096 * 2);
    unsigned short* wcombf = (unsigned short*)take((size_t)32768 * 2);
    unsigned short* wd1f   = (unsigned short*)take((size_t)10240 * 2);
    unsigned short* wd2f   = (unsigned short*)take((size_t)2048 * 2);
    (void)ws_size;

    k_setup<<<19696, 256, 0, stream>>>(root, Wih, Whh, We2, be2, Wd1, bd1, Wd2,
                                       x, u, Wp, bp, ea, We1, be1,
                                       rootTf, wcombf, w2tf, wd1f, wd2f,
                                       hb, hid, aggcnt);
    k_counts<<<128, 256, 0, stream>>>(ei, cnts);

    for (int s = 0; s < STEPS; s++) {
        k_msg_fused<<<N_EDGES / 64, 512, 0, stream>>>(hid, hb, w2tf, ei, agg);
        k_node<<<N_NODES / 64, 256, 0, stream>>>(hb, rootTf, wcombf, agg, cnts,
                                                 conv_b, bih, bhh, hb);
    }
    k_decoder<<<N_EDGES / 64, 256, 0, stream>>>(hb, ei, ea, wd1f, wd2f, bd2,
                                                Wd3, bd3, out);
}